// Round 8
// baseline (285.155 us; speedup 1.0000x reference)
//
#include <hip/hip_runtime.h>
#include <hip/hip_bf16.h>
#include <math.h>

// Problem constants
#define BB 8
#define SS 512
#define VV 32000
#define EE 256
#define NAx 12
#define NCc 24
#define NSt 576
#define MM (BB*SS)   // 4096

typedef __bf16 bf16x8 __attribute__((ext_vector_type(8)));
typedef float f32x4 __attribute__((ext_vector_type(4)));

#define MFMA16(a, b, c) __builtin_amdgcn_mfma_f32_16x16x32_bf16((a), (b), (c), 0, 0, 0)

__device__ __forceinline__ void gl2lds16(const void* g, void* l) {
  __builtin_amdgcn_global_load_lds(
      (const __attribute__((address_space(1))) void*)g,
      (__attribute__((address_space(3))) void*)l, 16, 0, 0);
}

#define FENCE() asm volatile("" ::: "memory")
#define BAR()   do { FENCE(); __builtin_amdgcn_s_barrier(); FENCE(); } while (0)

// ---------------- transpose f32 [R,C] -> bf16 [C,R], 64x64 tiles ----------
__global__ __launch_bounds__(256) void k_transpose64(
    const float* __restrict__ in, __hip_bfloat16* __restrict__ out, int R, int C)
{
  __shared__ float t[64][65];
  const int tx = threadIdx.x, ty = threadIdx.y;   // (64,4)
  const int c0 = blockIdx.x * 64, r0 = blockIdx.y * 64;
#pragma unroll
  for (int i = 0; i < 64; i += 4)
    t[ty + i][tx] = in[(size_t)(r0 + ty + i) * C + (c0 + tx)];
  __syncthreads();
#pragma unroll
  for (int i = 0; i < 64; i += 4)
    out[(size_t)(c0 + ty + i) * R + (r0 + tx)] = __float2bfloat16(t[tx][ty + i]);
}

// ---------------- embed -> axioms -> comps (f32) ----------------
__global__ __launch_bounds__(64) void k_embed_comps(
    const int* __restrict__ ids, const float* __restrict__ ET,
    const float* __restrict__ axw, const float* __restrict__ axb,
    const float* __restrict__ axg, const float* __restrict__ axbeta,
    const float* __restrict__ cw,  const float* __restrict__ cb,
    const float* __restrict__ cg,  const float* __restrict__ cbeta,
    float* __restrict__ comps)
{
  __shared__ float sw[EE * NAx];
  __shared__ float scw[NAx * NCc];
  const int tid = threadIdx.x;
  for (int i = tid; i < EE * NAx; i += 64) sw[i] = axw[i];
  for (int i = tid; i < NAx * NCc; i += 64) scw[i] = cw[i];
  __syncthreads();

  const int m = blockIdx.x * 64 + tid;
  const int id = ids[m];
  const float4* e4 = reinterpret_cast<const float4*>(ET + (size_t)id * EE);

  float a[NAx];
#pragma unroll
  for (int t = 0; t < NAx; ++t) a[t] = axb[t];

  for (int q = 0; q < EE / 4; ++q) {
    float4 v = e4[q];
#pragma unroll
    for (int c = 0; c < 4; ++c) {
      float x = (c == 0) ? v.x : (c == 1) ? v.y : (c == 2) ? v.z : v.w;
      const float* wrow = &sw[(q * 4 + c) * NAx];
#pragma unroll
      for (int t = 0; t < NAx; ++t) a[t] += x * wrow[t];
    }
  }
  {
    float mean = 0.f;
#pragma unroll
    for (int t = 0; t < NAx; ++t) mean += a[t];
    mean *= (1.0f / NAx);
    float var = 0.f;
#pragma unroll
    for (int t = 0; t < NAx; ++t) { float d = a[t] - mean; var += d * d; }
    var *= (1.0f / NAx);
    float rs = rsqrtf(var + 1e-5f);
#pragma unroll
    for (int t = 0; t < NAx; ++t)
      a[t] = tanhf((a[t] - mean) * rs * axg[t] + axbeta[t]);
  }
  float c24[NCc];
#pragma unroll
  for (int j = 0; j < NCc; ++j) c24[j] = cb[j];
#pragma unroll
  for (int t = 0; t < NAx; ++t) {
    float x = a[t];
    const float* wrow = &scw[t * NCc];
#pragma unroll
    for (int j = 0; j < NCc; ++j) c24[j] += x * wrow[j];
  }
  {
    float mean = 0.f;
#pragma unroll
    for (int j = 0; j < NCc; ++j) mean += c24[j];
    mean *= (1.0f / NCc);
    float var = 0.f;
#pragma unroll
    for (int j = 0; j < NCc; ++j) { float d = c24[j] - mean; var += d * d; }
    var *= (1.0f / NCc);
    float rs = rsqrtf(var + 1e-5f);
#pragma unroll
    for (int j = 0; j < NCc; ++j)
      c24[j] = tanhf((c24[j] - mean) * rs * cg[j] + cbeta[j]);
  }
#pragma unroll
  for (int j = 0; j < NCc; ++j) comps[(size_t)m * NCc + j] = c24[j];
}

// ---------------- state recurrence ----------------
__global__ __launch_bounds__(576) void k_recurrence(
    const float* __restrict__ comps, const float* __restrict__ mix,
    __hip_bfloat16* __restrict__ ST, float* __restrict__ fstate)
{
  __shared__ float sc[SS * NCc];
  const int b = blockIdx.x, tid = threadIdx.x;
  const float* src = comps + (size_t)b * SS * NCc;
  for (int i = tid; i < SS * NCc; i += 576) sc[i] = src[i];
  __syncthreads();

  const float sm = 1.0f / (1.0f + expf(-mix[0]));
  const int i = tid / NCc, j = tid - i * NCc;
  float st = 0.0f;
  __hip_bfloat16* stp = ST + (size_t)b * SS * NSt + tid;
  for (int t = 0; t < SS; ++t) {
    float ci = sc[t * NCc + i], cj = sc[t * NCc + j];
    st = 0.9f * st + sm * ci * cj;
    stp[(size_t)t * NSt] = __float2bfloat16(st);
  }
  fstate[b * NSt + tid] = st;
}

// ---------------- 128^2 bf16 GEMM (m97 structure) for GEMM1 ----------------
__global__ __launch_bounds__(256) void k_gemm_bt_gelu(
    const __hip_bfloat16* __restrict__ A,   // [M,K]
    const __hip_bfloat16* __restrict__ Bt,  // [N,K]
    const float* __restrict__ bias,
    __hip_bfloat16* __restrict__ Cb,
    int M, int N, int K)
{
  __shared__ __align__(16) __hip_bfloat16 As[128 * 32];
  __shared__ __align__(16) __hip_bfloat16 Bs[128 * 32];
  const int tid  = threadIdx.x;
  const int lane = tid & 63;
  const int w    = tid >> 6;
  const int wr   = w >> 1, wc = w & 1;
  const int m0 = blockIdx.y * 128;
  const int n0 = blockIdx.x * 128;
  const int lr = lane & 15;
  const int kb = lane >> 4;

  f32x4 acc[4][4];
#pragma unroll
  for (int i = 0; i < 4; ++i)
#pragma unroll
    for (int j = 0; j < 4; ++j) acc[i][j] = (f32x4){0.f, 0.f, 0.f, 0.f};

  for (int k0 = 0; k0 < K; k0 += 32) {
    __syncthreads();
#pragma unroll
    for (int p = 0; p < 2; ++p) {
      const int lbase = w * 2048 + p * 1024;
      const int o  = lbase + lane * 16;
      const int r  = o >> 6;
      const int sg = (o >> 4) & 3;
      gl2lds16(A  + (size_t)(m0 + r) * K + k0 + sg * 8, (char*)As + lbase);
      gl2lds16(Bt + (size_t)(n0 + r) * K + k0 + sg * 8, (char*)Bs + lbase);
    }
    asm volatile("s_waitcnt vmcnt(0)" ::: "memory");
    __syncthreads();

    bf16x8 af[4], bv[4];
#pragma unroll
    for (int mr = 0; mr < 4; ++mr)
      af[mr] = *reinterpret_cast<const bf16x8*>(&As[(wr * 64 + mr * 16 + lr) * 32 + kb * 8]);
#pragma unroll
    for (int nr = 0; nr < 4; ++nr)
      bv[nr] = *reinterpret_cast<const bf16x8*>(&Bs[(wc * 64 + nr * 16 + lr) * 32 + kb * 8]);
#pragma unroll
    for (int mr = 0; mr < 4; ++mr)
#pragma unroll
      for (int nr = 0; nr < 4; ++nr)
        acc[mr][nr] = MFMA16(af[mr], bv[nr], acc[mr][nr]);
  }

#pragma unroll
  for (int nr = 0; nr < 4; ++nr) {
    const int col = n0 + wc * 64 + nr * 16 + lr;
    const float bvs = bias[col];
#pragma unroll
    for (int mr = 0; mr < 4; ++mr) {
      const int rbase = m0 + wr * 64 + mr * 16 + kb * 4;
#pragma unroll
      for (int r = 0; r < 4; ++r) {
        float v = acc[mr][nr][r] + bvs;
        v = 0.5f * v * (1.0f + erff(v * 0.70710678118654752f));
        Cb[(size_t)(rbase + r) * N + col] = __float2bfloat16(v);
      }
    }
  }
}

// ---------------- GEMM2: 128(M)x256(N) tile, BK=32, 4 waves, 2 blocks/CU ----
// C[m][n] = sum_k A[m][k]*Bt[n][k] + bias[n], f32 NT out.
// 44 FLOP/B LDS intensity (256-class) + 2 blocks/CU overlap (128-class occ).
// Counted-vmcnt 2-deep: stage t+2 after mid-iter barrier (buf-c reads drained).
// Requires: M%128==0, N%256==0, K%32==0, K/32>=2, grid%8==0.
__global__ __launch_bounds__(256, 2) void k_gemm2_bk32(
    const __hip_bfloat16* __restrict__ A,   // [M,K]
    const __hip_bfloat16* __restrict__ Bt,  // [N,K]
    const float* __restrict__ bias,
    float* __restrict__ C,
    int M, int N, int K, int tiles_m)
{
  __shared__ __align__(16) char smem[49152];  // A: 2x8KB @0, B: 2x16KB @16384

  const int NK  = K >> 5;           // 16
  const int tid = threadIdx.x;
  const int lane = tid & 63;
  const int w  = tid >> 6;          // 0..3
  const int wr = w >> 1;            // M half (64 rows)
  const int wc = w & 1;             // N half (128 cols)
  const int lr = lane & 15;
  const int kb = lane >> 4;

  // T1: bijective XCD swizzle (grid % 8 == 0); mt fastest -> B panel L2-reuse
  const int nwg = gridDim.x;
  const int cpx = nwg >> 3;
  const int s   = ((int)blockIdx.x & 7) * cpx + ((int)blockIdx.x >> 3);
  const int nt  = s / tiles_m;
  const int mt  = s - nt * tiles_m;
  const int m0  = mt << 7;          // x128
  const int n0  = nt << 8;          // x256

  // stage-side source swizzle (lane-only; LDS dest linear)
  const int scol = (((lane & 3) ^ ((lane >> 3) & 3)) << 3);  // elements
  // read-side seg swizzle: 2-way (free) banks for 64B rows
  const int rsw  = ((kb ^ ((lr >> 1) & 3)) << 4);            // bytes

  // one STAGE instr: wave stages 16 rows x 32 cols region (1 KB)
#define STAGE_A(buf, j, tk0)                                               \
  gl2lds16(A + (size_t)(m0 + w*32 + (j)*16 + (lane >> 2)) * K + (tk0) + scol, \
           smem + (buf)*8192 + w*2048 + (j)*1024 + lane*16)
#define STAGE_B(buf, j, tk0)                                               \
  gl2lds16(Bt + (size_t)(n0 + w*64 + (j)*16 + (lane >> 2)) * K + (tk0) + scol, \
           smem + 16384 + (buf)*16384 + w*4096 + (j)*1024 + lane*16)

#define LDA(buf, mf) \
  (*(const bf16x8*)(smem + (buf)*8192 + (wr*64 + (mf)*16 + lr)*64 + rsw))
#define LDB(buf, nf) \
  (*(const bf16x8*)(smem + 16384 + (buf)*16384 + (wc*128 + (nf)*16 + lr)*64 + rsw))

  f32x4 acc[4][8];
#pragma unroll
  for (int i = 0; i < 4; ++i)
#pragma unroll
    for (int j = 0; j < 8; ++j) acc[i][j] = (f32x4){0.f, 0.f, 0.f, 0.f};

  float bvs[8];
#pragma unroll
  for (int nf = 0; nf < 8; ++nf) bvs[nf] = bias[n0 + wc * 128 + nf * 16 + lr];

  // ---- prologue: tile0 + tile1 (6 loads/thread each); wait oldest 6
  STAGE_A(0, 0, 0);  STAGE_A(0, 1, 0);
  STAGE_B(0, 0, 0);  STAGE_B(0, 1, 0);  STAGE_B(0, 2, 0);  STAGE_B(0, 3, 0);
  STAGE_A(1, 0, 32); STAGE_A(1, 1, 32);
  STAGE_B(1, 0, 32); STAGE_B(1, 1, 32); STAGE_B(1, 2, 32); STAGE_B(1, 3, 32);
  asm volatile("s_waitcnt vmcnt(6)" ::: "memory");   // tile0 landed
  BAR();

#pragma unroll 1
  for (int t = 0; t < NK; ++t) {
    const int c  = t & 1;
    const int k2 = (t + 2) << 5;
    bf16x8 a[4], b[8];

    // ---- half 1: read all frags of buf c; MFMA nf 0..3
#pragma unroll
    for (int mf = 0; mf < 4; ++mf) a[mf] = LDA(c, mf);
#pragma unroll
    for (int nf = 0; nf < 8; ++nf) b[nf] = LDB(c, nf);
    asm volatile("s_waitcnt lgkmcnt(0)" ::: "memory");
    __builtin_amdgcn_sched_barrier(0);
    __builtin_amdgcn_s_setprio(1);
#pragma unroll
    for (int mf = 0; mf < 4; ++mf) {
      acc[mf][0] = MFMA16(a[mf], b[0], acc[mf][0]);
      acc[mf][1] = MFMA16(a[mf], b[1], acc[mf][1]);
      acc[mf][2] = MFMA16(a[mf], b[2], acc[mf][2]);
      acc[mf][3] = MFMA16(a[mf], b[3], acc[mf][3]);
    }
    __builtin_amdgcn_s_setprio(0);
    BAR();   // all waves' buf-c reads drained (own lgkmcnt(0) above)

    // ---- half 2: stage tile t+2 into freed buf c; MFMA nf 4..7
    if (t < NK - 2) {
      STAGE_A(c, 0, k2); STAGE_A(c, 1, k2);
      STAGE_B(c, 0, k2); STAGE_B(c, 1, k2); STAGE_B(c, 2, k2); STAGE_B(c, 3, k2);
    }
    __builtin_amdgcn_s_setprio(1);
#pragma unroll
    for (int mf = 0; mf < 4; ++mf) {
      acc[mf][4] = MFMA16(a[mf], b[4], acc[mf][4]);
      acc[mf][5] = MFMA16(a[mf], b[5], acc[mf][5]);
      acc[mf][6] = MFMA16(a[mf], b[6], acc[mf][6]);
      acc[mf][7] = MFMA16(a[mf], b[7], acc[mf][7]);
    }
    __builtin_amdgcn_s_setprio(0);
    if (t < NK - 2) {
      asm volatile("s_waitcnt vmcnt(6)" ::: "memory");   // tile t+1 landed
    } else if (t == NK - 2) {
      asm volatile("s_waitcnt vmcnt(0)" ::: "memory");
    }
    BAR();
  }

  // ---- epilogue: direct NT scalar stores (overlapped by co-resident block)
#pragma unroll
  for (int nf = 0; nf < 8; ++nf) {
    const int col = n0 + wc * 128 + nf * 16 + lr;
#pragma unroll
    for (int mf = 0; mf < 4; ++mf) {
      const int rbase = m0 + wr * 64 + mf * 16 + kb * 4;
#pragma unroll
      for (int r = 0; r < 4; ++r)
        __builtin_nontemporal_store(acc[mf][nf][r] + bvs[nf],
                                    &C[(size_t)(rbase + r) * N + col]);
    }
  }
#undef STAGE_A
#undef STAGE_B
#undef LDA
#undef LDB
}

// ---------------- launch ----------------
extern "C" void kernel_launch(void* const* d_in, const int* in_sizes, int n_in,
                              void* d_out, int out_size, void* d_ws, size_t ws_size,
                              hipStream_t stream) {
  const int*   ids  = (const int*)  d_in[0];
  const float* ET   = (const float*)d_in[1];
  const float* axw  = (const float*)d_in[2];
  const float* axb  = (const float*)d_in[3];
  const float* axg  = (const float*)d_in[4];
  const float* axbt = (const float*)d_in[5];
  const float* cw   = (const float*)d_in[6];
  const float* cb   = (const float*)d_in[7];
  const float* cg   = (const float*)d_in[8];
  const float* cbt  = (const float*)d_in[9];
  const float* mix  = (const float*)d_in[10];
  const float* w1   = (const float*)d_in[11];
  const float* b1   = (const float*)d_in[12];
  const float* w2   = (const float*)d_in[13];
  const float* b2   = (const float*)d_in[14];

  float* out = (float*)d_out;

  char* ws = (char*)d_ws;
  size_t o = 0;
  __hip_bfloat16* W2T   = (__hip_bfloat16*)(ws + o); o += (size_t)VV * 512 * 2;
  __hip_bfloat16* W1T   = (__hip_bfloat16*)(ws + o); o += (size_t)512 * NSt * 2;
  float*          comps = (float*)(ws + o);          o += (size_t)MM * NCc * 4;
  __hip_bfloat16* STb   = (__hip_bfloat16*)(ws + o); o += (size_t)MM * NSt * 2;
  __hip_bfloat16* H     = (__hip_bfloat16*)(ws + o); o += (size_t)MM * 512 * 2;

  // W2 [512,32000] -> W2T bf16 [32000,512]; W1 [576,512] -> W1T bf16 [512,576]
  k_transpose64<<<dim3(VV / 64, 512 / 64), dim3(64, 4), 0, stream>>>(w2, W2T, 512, VV);
  k_transpose64<<<dim3(512 / 64, NSt / 64), dim3(64, 4), 0, stream>>>(w1, W1T, NSt, 512);

  k_embed_comps<<<MM / 64, 64, 0, stream>>>(ids, ET, axw, axb, axg, axbt,
                                            cw, cb, cg, cbt, comps);

  k_recurrence<<<BB, NSt, 0, stream>>>(comps, mix, STb, out + (size_t)MM * VV);

  // GEMM1: H = gelu(ST @ W1 + b1)  (M=4096, N=512, K=576)
  k_gemm_bt_gelu<<<dim3(512 / 128, MM / 128), 256, 0, stream>>>(
      STb, W1T, b1, H, MM, 512, NSt);

  // GEMM2: logits = H @ W2 + b2  (M=4096, N=32000, K=512)
  // 128x256 tile, BK=32, 2 blocks/CU; grid = 32*125 = 4000 (%8==0)
  k_gemm2_bk32<<<(MM / 128) * (VV / 256), 256, 0, stream>>>(
      H, W2T, b2, out, MM, VV, 512, MM / 128);
}